// Round 1
// 482.839 us; speedup vs baseline: 1.0174x; 1.0174x over previous
//
#include <hip/hip_runtime.h>

typedef float f32x4 __attribute__((ext_vector_type(4)));
typedef short s16x8 __attribute__((ext_vector_type(8)));

#define NT 32768      // tokens
#define NK 8192       // embeddings
#define ND 256        // dim
#define NSP 32        // column splits (NK/256)
#define NKT 12        // K-tiles: logical K=768, BK=64

// round-to-nearest-even fp32 -> bf16 bits
static __device__ __forceinline__ ushort f2bf(float f) {
  unsigned u = __float_as_uint(f);
  unsigned r = (u + 0x7FFFu + ((u >> 16) & 1u)) >> 16;
  return (ushort)r;
}

// ---------------- fp32 [rows][256] -> bf16 split [rows][512] = [hi(256) | lo(256)] ----
__global__ __launch_bounds__(256) void vq_cvt(const float* __restrict__ src,
                                              ushort* __restrict__ dst) {
  size_t idx = (size_t)blockIdx.x * 256 + threadIdx.x;
  size_t n = idx >> 6;
  int dq = (int)(idx & 63) * 4;
  float4 v = *reinterpret_cast<const float4*>(src + n * ND + dq);
  float f[4] = {v.x, v.y, v.z, v.w};
  ushort h[4], l[4];
#pragma unroll
  for (int t = 0; t < 4; ++t) {
    h[t] = f2bf(f[t]);
    float hf = __uint_as_float((unsigned)h[t] << 16);
    l[t] = f2bf(f[t] - hf);   // exact residual, then RN
  }
  *reinterpret_cast<ushort4*>(dst + n * 512 + dq) = make_ushort4(h[0], h[1], h[2], h[3]);
  *reinterpret_cast<ushort4*>(dst + n * 512 + 256 + dq) = make_ushort4(l[0], l[1], l[2], l[3]);
}

// ---------------- ||e_k||^2 (exact fp32) ----------------
__global__ __launch_bounds__(256) void vq_esq(const float* __restrict__ emb,
                                              float* __restrict__ esq) {
  int w = threadIdx.x >> 6, lane = threadIdx.x & 63;
  int k = blockIdx.x * 4 + w;
  const float4 e = *reinterpret_cast<const float4*>(emb + (size_t)k * ND + lane * 4);
  float s = e.x * e.x + e.y * e.y + e.z * e.z + e.w * e.w;
#pragma unroll
  for (int off = 32; off >= 1; off >>= 1) s += __shfl_down(s, off);
  if (lane == 0) esq[k] = s;
}

#define GL16(gp, lp)                                                              \
  __builtin_amdgcn_global_load_lds(                                               \
      (const __attribute__((address_space(1))) unsigned int*)(gp),                \
      (__attribute__((address_space(3))) unsigned int*)(lp), 16, 0, 0)

#define BAR()                                                                     \
  do {                                                                            \
    asm volatile("" ::: "memory");                                                \
    __builtin_amdgcn_s_barrier();                                                 \
    asm volatile("" ::: "memory");                                                \
  } while (0)

// K-tile -> element offset in the [hi(256)|lo(256)] layout.
// terms: 0: z_hi.e_hi (kt 0-3), 1: z_hi.e_lo (kt 4-7), 2: z_lo.e_hi (kt 8-11)
__device__ __forceinline__ int koffA(int kt) { return ((kt >= 8) ? 256 : 0) + (kt & 3) * 64; }
__device__ __forceinline__ int koffB(int kt) { return ((kt >= 4 && kt < 8) ? 256 : 0) + (kt & 3) * 64; }

// ---------------- 256x256 8-phase MFMA GEMM + per-tile argmin ----------------
// dist(n,k) = esq[k] - 2*cross   (z^2 row-constant, dropped)
__global__ __launch_bounds__(512, 2) void vq_mfma(
    const ushort* __restrict__ z2, const ushort* __restrict__ e2,
    const float* __restrict__ esq, float* __restrict__ pdist,
    int* __restrict__ pidx) {
  // A: [0,64K)  = [buf][khalf][256 rows][32 cols] bf16 (row stride 64B -> conflict-free b128 reads)
  // B: [64K,128K) same layout
  __shared__ __align__(16) char smem[131072];
  char* ldsA = smem;
  char* ldsB = smem + 65536;

  // XCD-aware swizzle: XCD x sweeps a 16-mt row panel across all 32 nt (A panel L2-hot)
  const int gid = blockIdx.x;
  const int x = gid & 7, c = gid >> 3;
  const int mt = x * 16 + (c >> 5);   // 0..127
  const int nt = c & 31;              // 0..31
  const int m0 = mt * 256, n0 = nt * 256;

  const int tid = threadIdx.x, lane = tid & 63, wid = tid >> 6;
  const int wr = wid >> 2, wc = wid & 3;        // 2 x 4 waves, per-wave 128x64 output
  const int fr = lane & 15, g = lane >> 4;

  // staging: thread t covers row (t>>2), 16B slot (t&3) of a 256x32 K-half (2 loads: +128 rows)
  const ushort* aBase = z2 + (size_t)(m0 + (tid >> 2)) * 512 + (tid & 3) * 8;
  const ushort* bBase = e2 + (size_t)(n0 + (tid >> 2)) * 512 + (tid & 3) * 8;

#define STAGE_A(kt, kh)                                                           \
  do {                                                                            \
    const ushort* _g = aBase + koffA(kt) + (kh) * 32;                             \
    char* _l = ldsA + (((kt) & 1) << 15) + ((kh) << 14) + tid * 16;               \
    GL16(_g, _l);                                                                 \
    GL16(_g + 65536, _l + 8192);                                                  \
  } while (0)
#define STAGE_B(kt, kh)                                                           \
  do {                                                                            \
    const ushort* _g = bBase + koffB(kt) + (kh) * 32;                             \
    char* _l = ldsB + (((kt) & 1) << 15) + ((kh) << 14) + tid * 16;               \
    GL16(_g, _l);                                                                 \
    GL16(_g + 65536, _l + 8192);                                                  \
  } while (0)

  // fragment-read bases: row*64 + g*16 within a K-half block
  const int aro = (wr * 128 + fr) * 64 + g * 16;
  const int bro = (wc * 64 + fr) * 64 + g * 16;

  f32x4 acc[8][4];
  const f32x4 zero = {0.f, 0.f, 0.f, 0.f};
#pragma unroll
  for (int i = 0; i < 8; ++i)
#pragma unroll
    for (int j = 0; j < 4; ++j) acc[i][j] = zero;

  // prologue: kt0 (4 halves) + kt1 first 3 halves; keep newest 3 in flight
  STAGE_A(0, 0); STAGE_B(0, 0); STAGE_A(0, 1); STAGE_B(0, 1);
  STAGE_A(1, 0); STAGE_B(1, 0); STAGE_A(1, 1);
  asm volatile("s_waitcnt vmcnt(6)" ::: "memory");
  BAR();

#define MMACC(J0, J1)                                                             \
  do {                                                                            \
    __builtin_amdgcn_s_setprio(1);                                                \
    _Pragma("unroll") for (int i = 0; i < 8; ++i) {                               \
      acc[i][J0] = __builtin_amdgcn_mfma_f32_16x16x32_bf16(af[i], b0, acc[i][J0], 0, 0, 0); \
      acc[i][J1] = __builtin_amdgcn_mfma_f32_16x16x32_bf16(af[i], b1, acc[i][J1], 0, 0, 0); \
    }                                                                             \
    __builtin_amdgcn_s_setprio(0);                                                \
  } while (0)

#pragma unroll 2
  for (int kt = 0; kt < NKT; ++kt) {
    const int bufo = (kt & 1) << 15;
    const char* pa = ldsA + bufo + aro;
    const char* pb = ldsB + bufo + bro;
    s16x8 af[8], b0, b1;

    // ---- phase 0: kk=0, j=0,1 ----
    b0 = *(const s16x8*)(pb);
    b1 = *(const s16x8*)(pb + 1024);
#pragma unroll
    for (int i = 0; i < 8; ++i) af[i] = *(const s16x8*)(pa + i * 1024);
    if (kt + 1 < NKT) STAGE_B(kt + 1, 1);   // B^1 Kh1: read at (kt-1) p2/p3
    BAR();
    MMACC(0, 1);
    BAR();

    // ---- phase 1: kk=0, j=2,3 ----
    b0 = *(const s16x8*)(pb + 2048);
    b1 = *(const s16x8*)(pb + 3072);
    if (kt + 2 < NKT) STAGE_A(kt + 2, 0);   // A cur-buf Kh0: read at p0
    BAR();
    MMACC(2, 3);
    BAR();

    // ---- phase 2: kk=1, j=0,1 ----
    b0 = *(const s16x8*)(pb + 16384);
    b1 = *(const s16x8*)(pb + 16384 + 1024);
#pragma unroll
    for (int i = 0; i < 8; ++i) af[i] = *(const s16x8*)(pa + 16384 + i * 1024);
    if (kt + 2 < NKT) STAGE_B(kt + 2, 0);   // B cur-buf Kh0: read at p0/p1
    BAR();
    MMACC(0, 1);
    BAR();

    // ---- phase 3: kk=1, j=2,3 ----
    b0 = *(const s16x8*)(pb + 16384 + 2048);
    b1 = *(const s16x8*)(pb + 16384 + 3072);
    if (kt + 2 < NKT) STAGE_A(kt + 2, 1);   // A cur-buf Kh1: read at p2
    BAR();
    MMACC(2, 3);
    // counted boundary wait: keep the 3 newest (kt+2) half-tiles in flight.
    if (kt == NKT - 2) {
      asm volatile("s_waitcnt vmcnt(0)" ::: "memory");   // last tile stages nothing
    } else {
      asm volatile("s_waitcnt vmcnt(6)" ::: "memory");
    }
    BAR();
  }

  // ---- epilogue: per-row argmin over this block's 256 cols ----
  float eqv[4];
#pragma unroll
  for (int j = 0; j < 4; ++j) eqv[j] = esq[n0 + wc * 64 + j * 16 + fr];

  float* rdv = (float*)smem;                              // [256][67] (pad -> ~conflict-free)
  unsigned char* rdc = (unsigned char*)(smem + 98304);    // [256][64]

#pragma unroll
  for (int i = 0; i < 8; ++i)
#pragma unroll
    for (int r = 0; r < 4; ++r) {
      float bv = 3.4e38f; int bc = 0;
#pragma unroll
      for (int j = 0; j < 4; ++j) {
        float dist = fmaf(-2.f, acc[i][j][r], eqv[j]);
        int cl = wc * 64 + j * 16 + fr;
        if (dist < bv) { bv = dist; bc = cl; }   // j ascending -> first-min kept
      }
      int row = wr * 128 + i * 16 + g * 4 + r;
      rdv[row * 67 + wc * 16 + fr] = bv;
      rdc[row * 64 + wc * 16 + fr] = (unsigned char)bc;
    }
  BAR();
  {
    const int row = tid >> 1, h = tid & 1;
    const float* pv = rdv + row * 67 + h * 32;
    const unsigned char* pc = rdc + row * 64 + h * 32;
    float bv = 3.4e38f; int bc = 256;
#pragma unroll
    for (int s = 0; s < 32; ++s) {
      float v = pv[s]; int cc = pc[s];
      if (v < bv || (v == bv && cc < bc)) { bv = v; bc = cc; }
    }
    float ov = __shfl_xor(bv, 1);
    int oc = __shfl_xor(bc, 1);
    if (ov < bv || (ov == bv && oc < bc)) { bv = ov; bc = oc; }
    if (h == 0) {
      int n = m0 + row;
      pdist[(size_t)n * NSP + nt] = bv;
      pidx[(size_t)n * NSP + nt] = n0 + bc;
    }
  }
}

// ---------------- merge partials, gather z_q, loss partials ----------------
__global__ __launch_bounds__(256) void vq_gather(
    const float* __restrict__ z, const float* __restrict__ emb,
    const float* __restrict__ pdist, const int* __restrict__ pidx,
    float* __restrict__ out, float* __restrict__ lpart) {
  int w = threadIdx.x >> 6, lane = threadIdx.x & 63;
  int n = blockIdx.x * 4 + w;
  int p = lane & (NSP - 1);
  float d = pdist[(size_t)n * NSP + p];
  int ii = pidx[(size_t)n * NSP + p];
#pragma unroll
  for (int off = 1; off < NSP; off <<= 1) {
    float od = __shfl_xor(d, off);
    int oi = __shfl_xor(ii, off);
    if (od < d || (od == d && oi < ii)) { d = od; ii = oi; }
  }
  int bi = ii;   // all lanes agree after butterfly (both 32-halves loaded same data)
  float4 q = *reinterpret_cast<const float4*>(emb + (size_t)bi * ND + lane * 4);
  float4 zz = *reinterpret_cast<const float4*>(z + (size_t)n * ND + lane * 4);
  *reinterpret_cast<float4*>(out + (size_t)n * ND + lane * 4) = q;  // z_q_st fwd == z_q
  float dx = zz.x - q.x, dy = zz.y - q.y, dz = zz.z - q.z, dw = zz.w - q.w;
  float s2 = dx * dx + dy * dy + dz * dz + dw * dw;
#pragma unroll
  for (int off = 32; off >= 1; off >>= 1) s2 += __shfl_down(s2, off);
  __shared__ float ls[4];
  if (lane == 0) {
    ls[w] = s2;
    out[(size_t)NT * ND + 1 + n] = (float)bi;  // indices as float
  }
  __syncthreads();
  if (threadIdx.x == 0) lpart[blockIdx.x] = ls[0] + ls[1] + ls[2] + ls[3];
}

// ---------------- deterministic loss finalize ----------------
__global__ __launch_bounds__(256) void vq_finalize(const float* __restrict__ lpart,
                                                   float* __restrict__ out) {
  __shared__ float s[256];
  float acc = 0.f;
  for (int i = threadIdx.x; i < NT / 4; i += 256) acc += lpart[i];
  s[threadIdx.x] = acc;
  __syncthreads();
  for (int st = 128; st >= 1; st >>= 1) {
    if (threadIdx.x < st) s[threadIdx.x] += s[threadIdx.x + st];
    __syncthreads();
  }
  if (threadIdx.x == 0)
    out[(size_t)NT * ND] = 1.25f * s[0] / (float)((size_t)NT * ND);
}

extern "C" void kernel_launch(void* const* d_in, const int* in_sizes, int n_in,
                              void* d_out, int out_size, void* d_ws, size_t ws_size,
                              hipStream_t stream) {
  const float* z = (const float*)d_in[0];    // (NT, ND) fp32
  const float* emb = (const float*)d_in[1];  // (NK, ND) fp32
  float* out = (float*)d_out;                // [z_q (NT*ND)] [loss (1)] [idx (NT)]

  float* esq = (float*)d_ws;                           // NK f32
  ushort* z2 = (ushort*)(esq + NK);                    // NT*512 bf16
  ushort* e2 = z2 + (size_t)NT * 512;                  // NK*512 bf16
  float* pdist = (float*)(e2 + (size_t)NK * 512);      // NT*NSP f32
  int* pidx = (int*)(pdist + (size_t)NT * NSP);        // NT*NSP i32
  float* lpart = (float*)(pidx + (size_t)NT * NSP);    // NT/4 f32

  vq_cvt<<<NT / 4, 256, 0, stream>>>(z, z2);
  vq_cvt<<<NK / 4, 256, 0, stream>>>(emb, e2);
  vq_esq<<<NK / 4, 256, 0, stream>>>(emb, esq);
  vq_mfma<<<4096, 512, 0, stream>>>(z2, e2, esq, pdist, pidx);
  vq_gather<<<NT / 4, 256, 0, stream>>>(z, emb, pdist, pidx, out, lpart);
  vq_finalize<<<1, 256, 0, stream>>>(lpart, out);
}

// Round 2
// 453.696 us; speedup vs baseline: 1.0827x; 1.0642x over previous
//
#include <hip/hip_runtime.h>

typedef float f32x4 __attribute__((ext_vector_type(4)));
typedef short s16x8 __attribute__((ext_vector_type(8)));

#define NT 32768      // tokens
#define NK 8192       // embeddings
#define ND 256        // dim
#define NSP 32        // column splits (NK/256)
#define NKT 12        // K-tiles: logical K=768, BK=64

// round-to-nearest-even fp32 -> bf16 bits
static __device__ __forceinline__ ushort f2bf(float f) {
  unsigned u = __float_as_uint(f);
  unsigned r = (u + 0x7FFFu + ((u >> 16) & 1u)) >> 16;
  return (ushort)r;
}

// ---------------- fp32 [rows][256] -> bf16 split [rows][512] = [hi(256) | lo(256)] ----
__global__ __launch_bounds__(256) void vq_cvt(const float* __restrict__ src,
                                              ushort* __restrict__ dst) {
  size_t idx = (size_t)blockIdx.x * 256 + threadIdx.x;
  size_t n = idx >> 6;
  int dq = (int)(idx & 63) * 4;
  float4 v = *reinterpret_cast<const float4*>(src + n * ND + dq);
  float f[4] = {v.x, v.y, v.z, v.w};
  ushort h[4], l[4];
#pragma unroll
  for (int t = 0; t < 4; ++t) {
    h[t] = f2bf(f[t]);
    float hf = __uint_as_float((unsigned)h[t] << 16);
    l[t] = f2bf(f[t] - hf);   // exact residual, then RN
  }
  *reinterpret_cast<ushort4*>(dst + n * 512 + dq) = make_ushort4(h[0], h[1], h[2], h[3]);
  *reinterpret_cast<ushort4*>(dst + n * 512 + 256 + dq) = make_ushort4(l[0], l[1], l[2], l[3]);
}

// ---------------- ||e_k||^2 (exact fp32) ----------------
__global__ __launch_bounds__(256) void vq_esq(const float* __restrict__ emb,
                                              float* __restrict__ esq) {
  int w = threadIdx.x >> 6, lane = threadIdx.x & 63;
  int k = blockIdx.x * 4 + w;
  const float4 e = *reinterpret_cast<const float4*>(emb + (size_t)k * ND + lane * 4);
  float s = e.x * e.x + e.y * e.y + e.z * e.z + e.w * e.w;
#pragma unroll
  for (int off = 32; off >= 1; off >>= 1) s += __shfl_down(s, off);
  if (lane == 0) esq[k] = s;
}

#define GL16(gp, lp)                                                              \
  __builtin_amdgcn_global_load_lds(                                               \
      (const __attribute__((address_space(1))) unsigned int*)(gp),                \
      (__attribute__((address_space(3))) unsigned int*)(lp), 16, 0, 0)

#define BAR()                                                                     \
  do {                                                                            \
    asm volatile("" ::: "memory");                                                \
    __builtin_amdgcn_s_barrier();                                                 \
    asm volatile("" ::: "memory");                                                \
  } while (0)

// K-tile -> element offset in the [hi(256)|lo(256)] layout.
// terms: 0: z_hi.e_hi (kt 0-3), 1: z_hi.e_lo (kt 4-7), 2: z_lo.e_hi (kt 8-11)
__device__ __forceinline__ int koffA(int kt) { return ((kt >= 8) ? 256 : 0) + (kt & 3) * 64; }
__device__ __forceinline__ int koffB(int kt) { return ((kt >= 4 && kt < 8) ? 256 : 0) + (kt & 3) * 64; }

// ---------------- 256x256 8-phase MFMA GEMM + per-tile argmin ----------------
// dist(n,k) = esq[k] - 2*cross   (z^2 row-constant, dropped)
__global__ __launch_bounds__(512, 2) void vq_mfma(
    const ushort* __restrict__ z2, const ushort* __restrict__ e2,
    const float* __restrict__ esq, float* __restrict__ pdist,
    int* __restrict__ pidx) {
  // A: [0,64K)  = [buf][khalf][256 rows][4 slots x 16B] bf16, slot-swizzled:
  //   phys slot p of row r holds logical k-slot p ^ ((r>>1)&3)  (quarter-wave
  //   b128 reads then hit all 8 bank-groups x 2 lanes = conflict-free)
  // B: [64K,128K) same layout
  __shared__ __align__(16) char smem[131072];
  char* ldsA = smem;
  char* ldsB = smem + 65536;

  // XCD-aware 8x8 supertile swizzle: each XCD owns 8 supertiles (2MB A + 2MB B panels fit 4MiB L2)
  const int gid = blockIdx.x;
  const int x = gid & 7, c = gid >> 3;        // 512 blocks per XCD
  const int S = x * 8 + (c >> 6);             // global supertile 0..63
  const int wi = c & 63;
  const int mt = (S >> 2) * 8 + (wi >> 3);    // 0..127
  const int nt = (S & 3) * 8 + (wi & 7);      // 0..31
  const int m0 = mt * 256, n0 = nt * 256;

  const int tid = threadIdx.x, lane = tid & 63, wid = tid >> 6;
  const int wr = wid >> 2, wc = wid & 3;        // 2 x 4 waves, per-wave 128x64 output
  const int fr = lane & 15, g = lane >> 4;

  // staging: thread t covers row (t>>2), phys 16B slot (t&3); fetch the logical
  // slot that belongs there: sslot = (t&3) ^ ((row>>1)&3) = (t&3) ^ ((t>>3)&3)
  const int sslot = (tid & 3) ^ ((tid >> 3) & 3);
  const ushort* aBase = z2 + (size_t)(m0 + (tid >> 2)) * 512 + sslot * 8;
  const ushort* bBase = e2 + (size_t)(n0 + (tid >> 2)) * 512 + sslot * 8;

#define STAGE_A(kt, kh)                                                           \
  do {                                                                            \
    const ushort* _g = aBase + koffA(kt) + (kh) * 32;                             \
    char* _l = ldsA + (((kt) & 1) << 15) + ((kh) << 14) + tid * 16;               \
    GL16(_g, _l);                                                                 \
    GL16(_g + 65536, _l + 8192);                                                  \
  } while (0)
#define STAGE_B(kt, kh)                                                           \
  do {                                                                            \
    const ushort* _g = bBase + koffB(kt) + (kh) * 32;                             \
    char* _l = ldsB + (((kt) & 1) << 15) + ((kh) << 14) + tid * 16;               \
    GL16(_g, _l);                                                                 \
    GL16(_g + 65536, _l + 8192);                                                  \
  } while (0)

  // fragment-read bases: row*64 + swizzled-slot*16 within a K-half block
  const int lbyte = fr * 64 + (((g ^ (fr >> 1)) & 3) << 4);
  const int aro = wr * 8192 + lbyte;
  const int bro = wc * 4096 + lbyte;

  f32x4 acc[8][4];
  const f32x4 zero = {0.f, 0.f, 0.f, 0.f};
#pragma unroll
  for (int i = 0; i < 8; ++i)
#pragma unroll
    for (int j = 0; j < 4; ++j) acc[i][j] = zero;

  // prologue: kt0 (4 halves) + kt1 first 3 halves; keep newest 3 in flight
  STAGE_A(0, 0); STAGE_B(0, 0); STAGE_A(0, 1); STAGE_B(0, 1);
  STAGE_A(1, 0); STAGE_B(1, 0); STAGE_A(1, 1);
  asm volatile("s_waitcnt vmcnt(6)" ::: "memory");
  BAR();

#define MMACC(J0, J1)                                                             \
  do {                                                                            \
    __builtin_amdgcn_s_setprio(1);                                                \
    _Pragma("unroll") for (int i = 0; i < 8; ++i) {                               \
      acc[i][J0] = __builtin_amdgcn_mfma_f32_16x16x32_bf16(af[i], b0, acc[i][J0], 0, 0, 0); \
      acc[i][J1] = __builtin_amdgcn_mfma_f32_16x16x32_bf16(af[i], b1, acc[i][J1], 0, 0, 0); \
    }                                                                             \
    __builtin_amdgcn_s_setprio(0);                                                \
  } while (0)

#pragma unroll 2
  for (int kt = 0; kt < NKT; ++kt) {
    const int bufo = (kt & 1) << 15;
    const char* pa = ldsA + bufo + aro;
    const char* pb = ldsB + bufo + bro;
    s16x8 af[8], b0, b1;

    // ---- phase 0: kk=0, j=0,1 ----
    b0 = *(const s16x8*)(pb);
    b1 = *(const s16x8*)(pb + 1024);
#pragma unroll
    for (int i = 0; i < 8; ++i) af[i] = *(const s16x8*)(pa + i * 1024);
    if (kt + 1 < NKT) STAGE_B(kt + 1, 1);   // B^1 Kh1: read at (kt+1) p2/p3
    BAR();
    MMACC(0, 1);
    BAR();

    // ---- phase 1: kk=0, j=2,3 ----
    b0 = *(const s16x8*)(pb + 2048);
    b1 = *(const s16x8*)(pb + 3072);
    if (kt + 2 < NKT) STAGE_A(kt + 2, 0);   // A cur-buf Kh0: read at (kt+2) p0
    BAR();
    MMACC(2, 3);
    BAR();

    // ---- phase 2: kk=1, j=0,1 ----
    b0 = *(const s16x8*)(pb + 16384);
    b1 = *(const s16x8*)(pb + 16384 + 1024);
#pragma unroll
    for (int i = 0; i < 8; ++i) af[i] = *(const s16x8*)(pa + 16384 + i * 1024);
    if (kt + 2 < NKT) STAGE_B(kt + 2, 0);   // B cur-buf Kh0: read at (kt+2) p0/p1
    BAR();
    MMACC(0, 1);
    BAR();

    // ---- phase 3: kk=1, j=2,3 ----
    b0 = *(const s16x8*)(pb + 16384 + 2048);
    b1 = *(const s16x8*)(pb + 16384 + 3072);
    if (kt + 2 < NKT) STAGE_A(kt + 2, 1);   // A cur-buf Kh1: read at (kt+2) p2
    BAR();
    MMACC(2, 3);
    // counted boundary wait: keep the 3 newest (kt+2) half-tiles in flight.
    if (kt == NKT - 2) {
      asm volatile("s_waitcnt vmcnt(0)" ::: "memory");   // last tile stages nothing
    } else {
      asm volatile("s_waitcnt vmcnt(6)" ::: "memory");
    }
    BAR();
  }

  // ---- epilogue: per-row argmin over this block's 256 cols ----
  float eqv[4];
#pragma unroll
  for (int j = 0; j < 4; ++j) eqv[j] = esq[n0 + wc * 64 + j * 16 + fr];

  float* rdv = (float*)smem;                              // [256][67] (pad -> ~conflict-free)
  unsigned char* rdc = (unsigned char*)(smem + 98304);    // [256][64]

#pragma unroll
  for (int i = 0; i < 8; ++i)
#pragma unroll
    for (int r = 0; r < 4; ++r) {
      float bv = 3.4e38f; int bc = 0;
#pragma unroll
      for (int j = 0; j < 4; ++j) {
        float dist = fmaf(-2.f, acc[i][j][r], eqv[j]);
        int cl = wc * 64 + j * 16 + fr;
        if (dist < bv) { bv = dist; bc = cl; }   // j ascending -> first-min kept
      }
      int row = wr * 128 + i * 16 + g * 4 + r;
      rdv[row * 67 + wc * 16 + fr] = bv;
      rdc[row * 64 + wc * 16 + fr] = (unsigned char)bc;
    }
  BAR();
  {
    const int row = tid >> 1, h = tid & 1;
    const float* pv = rdv + row * 67 + h * 32;
    const unsigned char* pc = rdc + row * 64 + h * 32;
    float bv = 3.4e38f; int bc = 256;
#pragma unroll
    for (int s = 0; s < 32; ++s) {
      float v = pv[s]; int cc = pc[s];
      if (v < bv || (v == bv && cc < bc)) { bv = v; bc = cc; }
    }
    float ov = __shfl_xor(bv, 1);
    int oc = __shfl_xor(bc, 1);
    if (ov < bv || (ov == bv && oc < bc)) { bv = ov; bc = oc; }
    if (h == 0) {
      int n = m0 + row;
      pdist[(size_t)n * NSP + nt] = bv;
      pidx[(size_t)n * NSP + nt] = n0 + bc;
    }
  }
}

// ---------------- merge partials, gather z_q, loss partials ----------------
__global__ __launch_bounds__(256) void vq_gather(
    const float* __restrict__ z, const float* __restrict__ emb,
    const float* __restrict__ pdist, const int* __restrict__ pidx,
    float* __restrict__ out, float* __restrict__ lpart) {
  int w = threadIdx.x >> 6, lane = threadIdx.x & 63;
  int n = blockIdx.x * 4 + w;
  int p = lane & (NSP - 1);
  float d = pdist[(size_t)n * NSP + p];
  int ii = pidx[(size_t)n * NSP + p];
#pragma unroll
  for (int off = 1; off < NSP; off <<= 1) {
    float od = __shfl_xor(d, off);
    int oi = __shfl_xor(ii, off);
    if (od < d || (od == d && oi < ii)) { d = od; ii = oi; }
  }
  int bi = ii;   // all lanes agree after butterfly (both 32-halves loaded same data)
  float4 q = *reinterpret_cast<const float4*>(emb + (size_t)bi * ND + lane * 4);
  float4 zz = *reinterpret_cast<const float4*>(z + (size_t)n * ND + lane * 4);
  *reinterpret_cast<float4*>(out + (size_t)n * ND + lane * 4) = q;  // z_q_st fwd == z_q
  float dx = zz.x - q.x, dy = zz.y - q.y, dz = zz.z - q.z, dw = zz.w - q.w;
  float s2 = dx * dx + dy * dy + dz * dz + dw * dw;
#pragma unroll
  for (int off = 32; off >= 1; off >>= 1) s2 += __shfl_down(s2, off);
  __shared__ float ls[4];
  if (lane == 0) {
    ls[w] = s2;
    out[(size_t)NT * ND + 1 + n] = (float)bi;  // indices as float
  }
  __syncthreads();
  if (threadIdx.x == 0) lpart[blockIdx.x] = ls[0] + ls[1] + ls[2] + ls[3];
}

// ---------------- deterministic loss finalize ----------------
__global__ __launch_bounds__(256) void vq_finalize(const float* __restrict__ lpart,
                                                   float* __restrict__ out) {
  __shared__ float s[256];
  float acc = 0.f;
  for (int i = threadIdx.x; i < NT / 4; i += 256) acc += lpart[i];
  s[threadIdx.x] = acc;
  __syncthreads();
  for (int st = 128; st >= 1; st >>= 1) {
    if (threadIdx.x < st) s[threadIdx.x] += s[threadIdx.x + st];
    __syncthreads();
  }
  if (threadIdx.x == 0)
    out[(size_t)NT * ND] = 1.25f * s[0] / (float)((size_t)NT * ND);
}

extern "C" void kernel_launch(void* const* d_in, const int* in_sizes, int n_in,
                              void* d_out, int out_size, void* d_ws, size_t ws_size,
                              hipStream_t stream) {
  const float* z = (const float*)d_in[0];    // (NT, ND) fp32
  const float* emb = (const float*)d_in[1];  // (NK, ND) fp32
  float* out = (float*)d_out;                // [z_q (NT*ND)] [loss (1)] [idx (NT)]

  float* esq = (float*)d_ws;                           // NK f32
  ushort* z2 = (ushort*)(esq + NK);                    // NT*512 bf16
  ushort* e2 = z2 + (size_t)NT * 512;                  // NK*512 bf16
  float* pdist = (float*)(e2 + (size_t)NK * 512);      // NT*NSP f32
  int* pidx = (int*)(pdist + (size_t)NT * NSP);        // NT*NSP i32
  float* lpart = (float*)(pidx + (size_t)NT * NSP);    // NT/4 f32

  vq_cvt<<<NT / 4, 256, 0, stream>>>(z, z2);
  vq_cvt<<<NK / 4, 256, 0, stream>>>(emb, e2);
  vq_esq<<<NK / 4, 256, 0, stream>>>(emb, esq);
  vq_mfma<<<4096, 512, 0, stream>>>(z2, e2, esq, pdist, pidx);
  vq_gather<<<NT / 4, 256, 0, stream>>>(z, emb, pdist, pidx, out, lpart);
  vq_finalize<<<1, 256, 0, stream>>>(lpart, out);
}

// Round 3
// 447.672 us; speedup vs baseline: 1.0973x; 1.0135x over previous
//
#include <hip/hip_runtime.h>

typedef float f32x4 __attribute__((ext_vector_type(4)));
typedef short s16x8 __attribute__((ext_vector_type(8)));

#define NT 32768      // tokens
#define NK 8192       // embeddings
#define ND 256        // dim
#define NSP 32        // column splits (NK/256)
#define NKT 12        // K-tiles: logical K=768, BK=64

// round-to-nearest-even fp32 -> bf16 bits
static __device__ __forceinline__ ushort f2bf(float f) {
  unsigned u = __float_as_uint(f);
  unsigned r = (u + 0x7FFFu + ((u >> 16) & 1u)) >> 16;
  return (ushort)r;
}

// ---------------- fp32 [rows][256] -> bf16 split [rows][512] = [hi(256) | lo(256)] ----
__global__ __launch_bounds__(256) void vq_cvt(const float* __restrict__ src,
                                              ushort* __restrict__ dst) {
  size_t idx = (size_t)blockIdx.x * 256 + threadIdx.x;
  size_t n = idx >> 6;
  int dq = (int)(idx & 63) * 4;
  float4 v = *reinterpret_cast<const float4*>(src + n * ND + dq);
  float f[4] = {v.x, v.y, v.z, v.w};
  ushort h[4], l[4];
#pragma unroll
  for (int t = 0; t < 4; ++t) {
    h[t] = f2bf(f[t]);
    float hf = __uint_as_float((unsigned)h[t] << 16);
    l[t] = f2bf(f[t] - hf);   // exact residual, then RN
  }
  *reinterpret_cast<ushort4*>(dst + n * 512 + dq) = make_ushort4(h[0], h[1], h[2], h[3]);
  *reinterpret_cast<ushort4*>(dst + n * 512 + 256 + dq) = make_ushort4(l[0], l[1], l[2], l[3]);
}

// ---------------- ||e_k||^2 (exact fp32) ----------------
__global__ __launch_bounds__(256) void vq_esq(const float* __restrict__ emb,
                                              float* __restrict__ esq) {
  int w = threadIdx.x >> 6, lane = threadIdx.x & 63;
  int k = blockIdx.x * 4 + w;
  const float4 e = *reinterpret_cast<const float4*>(emb + (size_t)k * ND + lane * 4);
  float s = e.x * e.x + e.y * e.y + e.z * e.z + e.w * e.w;
#pragma unroll
  for (int off = 32; off >= 1; off >>= 1) s += __shfl_down(s, off);
  if (lane == 0) esq[k] = s;
}

#define GL16(gp, lp)                                                              \
  __builtin_amdgcn_global_load_lds(                                               \
      (const __attribute__((address_space(1))) unsigned int*)(gp),                \
      (__attribute__((address_space(3))) unsigned int*)(lp), 16, 0, 0)

#define BAR()                                                                     \
  do {                                                                            \
    asm volatile("" ::: "memory");                                                \
    __builtin_amdgcn_s_barrier();                                                 \
    asm volatile("" ::: "memory");                                                \
  } while (0)

// K-tile -> element offset in the [hi(256)|lo(256)] layout.
// terms: 0: z_hi.e_hi (kt 0-3), 1: z_hi.e_lo (kt 4-7), 2: z_lo.e_hi (kt 8-11)
__device__ __forceinline__ int koffA(int kt) { return ((kt >= 8) ? 256 : 0) + (kt & 3) * 64; }
__device__ __forceinline__ int koffB(int kt) { return ((kt >= 4 && kt < 8) ? 256 : 0) + (kt & 3) * 64; }

// ---------------- 256x256 MFMA GEMM (1 barrier per K-tile) + per-tile argmin ----------------
// dist(n,k) = esq[k] - 2*cross   (z^2 row-constant, dropped)
__global__ __launch_bounds__(512, 2) void vq_mfma(
    const ushort* __restrict__ z2, const ushort* __restrict__ e2,
    const float* __restrict__ esq, float* __restrict__ pdist,
    int* __restrict__ pidx) {
  // A: [0,64K)  = [buf][khalf][256 rows][4 slots x 16B] bf16, slot-swizzled:
  //   phys slot p of row r holds logical k-slot p ^ ((r>>1)&3)  (quarter-wave
  //   b128 reads then hit all 8 bank-groups = minimal aliasing)
  // B: [64K,128K) same layout
  __shared__ __align__(16) char smem[131072];
  char* ldsA = smem;
  char* ldsB = smem + 65536;

  // XCD-aware 8x8 supertile swizzle: each XCD owns 8 supertiles (2MB A + 2MB B panels fit 4MiB L2)
  const int gid = blockIdx.x;
  const int x = gid & 7, c = gid >> 3;        // 512 blocks per XCD
  const int S = x * 8 + (c >> 6);             // global supertile 0..63
  const int wi = c & 63;
  const int mt = (S >> 2) * 8 + (wi >> 3);    // 0..127
  const int nt = (S & 3) * 8 + (wi & 7);      // 0..31
  const int m0 = mt * 256, n0 = nt * 256;

  const int tid = threadIdx.x, lane = tid & 63, wid = tid >> 6;
  const int wr = wid >> 2, wc = wid & 3;        // 2 x 4 waves, per-wave 128x64 output
  const int fr = lane & 15, g = lane >> 4;

  // staging: thread t covers row (t>>2), phys 16B slot (t&3); fetch the logical
  // slot that belongs there: sslot = (t&3) ^ ((row>>1)&3) = (t&3) ^ ((t>>3)&3)
  const int sslot = (tid & 3) ^ ((tid >> 3) & 3);
  const ushort* aBase = z2 + (size_t)(m0 + (tid >> 2)) * 512 + sslot * 8;
  const ushort* bBase = e2 + (size_t)(n0 + (tid >> 2)) * 512 + sslot * 8;

#define STAGE_A(kt, kh)                                                           \
  do {                                                                            \
    const ushort* _g = aBase + koffA(kt) + (kh) * 32;                             \
    char* _l = ldsA + (((kt) & 1) << 15) + ((kh) << 14) + tid * 16;               \
    GL16(_g, _l);                                                                 \
    GL16(_g + 65536, _l + 8192);                                                  \
  } while (0)
#define STAGE_B(kt, kh)                                                           \
  do {                                                                            \
    const ushort* _g = bBase + koffB(kt) + (kh) * 32;                             \
    char* _l = ldsB + (((kt) & 1) << 15) + ((kh) << 14) + tid * 16;               \
    GL16(_g, _l);                                                                 \
    GL16(_g + 65536, _l + 8192);                                                  \
  } while (0)

  // fragment-read bases: row*64 + swizzled-slot*16 within a K-half block
  const int lbyte = fr * 64 + (((g ^ (fr >> 1)) & 3) << 4);
  const int aro = wr * 8192 + lbyte;
  const int bro = wc * 4096 + lbyte;

  f32x4 acc[8][4];
  const f32x4 zero = {0.f, 0.f, 0.f, 0.f};
#pragma unroll
  for (int i = 0; i < 8; ++i)
#pragma unroll
    for (int j = 0; j < 4; ++j) acc[i][j] = zero;

  // prologue: stage kt0 into buf0, drain, barrier
  STAGE_A(0, 0); STAGE_B(0, 0); STAGE_A(0, 1); STAGE_B(0, 1);
  asm volatile("s_waitcnt vmcnt(0)" ::: "memory");
  BAR();

  // main loop: one barrier per K-tile; compiler interleaves ds_read/MFMA freely.
  // Hazard analysis: kt's stages write buf[(kt+1)&1], whose last readers (kt-1)
  // were drained by the lgkmcnt(0)+barrier at the end of kt-1. kt's reads come
  // from buf[kt&1], staged during kt-1 and drained by vmcnt(0) before the same
  // barrier. Stages issue at the TOP of the body (~3000 cyc before the drain),
  // so the end-of-tile vmcnt(0) is effectively free.
#pragma unroll 2
  for (int kt = 0; kt < NKT; ++kt) {
    const int bufo = (kt & 1) << 15;
    const char* pa = ldsA + bufo + aro;
    const char* pb = ldsB + bufo + bro;

    if (kt + 1 < NKT) {
      STAGE_A(kt + 1, 0); STAGE_B(kt + 1, 0);
      STAGE_A(kt + 1, 1); STAGE_B(kt + 1, 1);
    }

    s16x8 af[8], bf[4];
    // kk = 0
#pragma unroll
    for (int j = 0; j < 4; ++j) bf[j] = *(const s16x8*)(pb + j * 1024);
#pragma unroll
    for (int i = 0; i < 8; ++i) af[i] = *(const s16x8*)(pa + i * 1024);
#pragma unroll
    for (int i = 0; i < 8; ++i)
#pragma unroll
      for (int j = 0; j < 4; ++j)
        acc[i][j] = __builtin_amdgcn_mfma_f32_16x16x32_bf16(af[i], bf[j], acc[i][j], 0, 0, 0);
    // kk = 1
#pragma unroll
    for (int j = 0; j < 4; ++j) bf[j] = *(const s16x8*)(pb + 16384 + j * 1024);
#pragma unroll
    for (int i = 0; i < 8; ++i) af[i] = *(const s16x8*)(pa + 16384 + i * 1024);
#pragma unroll
    for (int i = 0; i < 8; ++i)
#pragma unroll
      for (int j = 0; j < 4; ++j)
        acc[i][j] = __builtin_amdgcn_mfma_f32_16x16x32_bf16(af[i], bf[j], acc[i][j], 0, 0, 0);

    // end-of-tile drain: all LDS reads consumed, all stages landed, then barrier.
    // sched_barrier(0) stops MFMAs from sinking past the drain (rule #18).
    asm volatile("s_waitcnt vmcnt(0) lgkmcnt(0)" ::: "memory");
    __builtin_amdgcn_sched_barrier(0);
    BAR();
  }

  // ---- epilogue: per-row argmin over this block's 256 cols ----
  float eqv[4];
#pragma unroll
  for (int j = 0; j < 4; ++j) eqv[j] = esq[n0 + wc * 64 + j * 16 + fr];

  float* rdv = (float*)smem;                              // [256][67] (pad -> ~conflict-free)
  unsigned char* rdc = (unsigned char*)(smem + 98304);    // [256][64]

#pragma unroll
  for (int i = 0; i < 8; ++i)
#pragma unroll
    for (int r = 0; r < 4; ++r) {
      float bv = 3.4e38f; int bc = 0;
#pragma unroll
      for (int j = 0; j < 4; ++j) {
        float dist = fmaf(-2.f, acc[i][j][r], eqv[j]);
        int cl = wc * 64 + j * 16 + fr;
        if (dist < bv) { bv = dist; bc = cl; }   // j ascending -> first-min kept
      }
      int row = wr * 128 + i * 16 + g * 4 + r;
      rdv[row * 67 + wc * 16 + fr] = bv;
      rdc[row * 64 + wc * 16 + fr] = (unsigned char)bc;
    }
  BAR();
  {
    const int row = tid >> 1, h = tid & 1;
    const float* pv = rdv + row * 67 + h * 32;
    const unsigned char* pc = rdc + row * 64 + h * 32;
    float bv = 3.4e38f; int bc = 256;
#pragma unroll
    for (int s = 0; s < 32; ++s) {
      float v = pv[s]; int cc = pc[s];
      if (v < bv || (v == bv && cc < bc)) { bv = v; bc = cc; }
    }
    float ov = __shfl_xor(bv, 1);
    int oc = __shfl_xor(bc, 1);
    if (ov < bv || (ov == bv && oc < bc)) { bv = ov; bc = oc; }
    if (h == 0) {
      int n = m0 + row;
      pdist[(size_t)n * NSP + nt] = bv;
      pidx[(size_t)n * NSP + nt] = n0 + bc;
    }
  }
}

// ---------------- merge partials, gather z_q, loss partials ----------------
__global__ __launch_bounds__(256) void vq_gather(
    const float* __restrict__ z, const float* __restrict__ emb,
    const float* __restrict__ pdist, const int* __restrict__ pidx,
    float* __restrict__ out, float* __restrict__ lpart) {
  int w = threadIdx.x >> 6, lane = threadIdx.x & 63;
  int n = blockIdx.x * 4 + w;
  int p = lane & (NSP - 1);
  float d = pdist[(size_t)n * NSP + p];
  int ii = pidx[(size_t)n * NSP + p];
#pragma unroll
  for (int off = 1; off < NSP; off <<= 1) {
    float od = __shfl_xor(d, off);
    int oi = __shfl_xor(ii, off);
    if (od < d || (od == d && oi < ii)) { d = od; ii = oi; }
  }
  int bi = ii;   // all lanes agree after butterfly (both 32-halves loaded same data)
  float4 q = *reinterpret_cast<const float4*>(emb + (size_t)bi * ND + lane * 4);
  float4 zz = *reinterpret_cast<const float4*>(z + (size_t)n * ND + lane * 4);
  *reinterpret_cast<float4*>(out + (size_t)n * ND + lane * 4) = q;  // z_q_st fwd == z_q
  float dx = zz.x - q.x, dy = zz.y - q.y, dz = zz.z - q.z, dw = zz.w - q.w;
  float s2 = dx * dx + dy * dy + dz * dz + dw * dw;
#pragma unroll
  for (int off = 32; off >= 1; off >>= 1) s2 += __shfl_down(s2, off);
  __shared__ float ls[4];
  if (lane == 0) {
    ls[w] = s2;
    out[(size_t)NT * ND + 1 + n] = (float)bi;  // indices as float
  }
  __syncthreads();
  if (threadIdx.x == 0) lpart[blockIdx.x] = ls[0] + ls[1] + ls[2] + ls[3];
}

// ---------------- deterministic loss finalize ----------------
__global__ __launch_bounds__(256) void vq_finalize(const float* __restrict__ lpart,
                                                   float* __restrict__ out) {
  __shared__ float s[256];
  float acc = 0.f;
  for (int i = threadIdx.x; i < NT / 4; i += 256) acc += lpart[i];
  s[threadIdx.x] = acc;
  __syncthreads();
  for (int st = 128; st >= 1; st >>= 1) {
    if (threadIdx.x < st) s[threadIdx.x] += s[threadIdx.x + st];
    __syncthreads();
  }
  if (threadIdx.x == 0)
    out[(size_t)NT * ND] = 1.25f * s[0] / (float)((size_t)NT * ND);
}

extern "C" void kernel_launch(void* const* d_in, const int* in_sizes, int n_in,
                              void* d_out, int out_size, void* d_ws, size_t ws_size,
                              hipStream_t stream) {
  const float* z = (const float*)d_in[0];    // (NT, ND) fp32
  const float* emb = (const float*)d_in[1];  // (NK, ND) fp32
  float* out = (float*)d_out;                // [z_q (NT*ND)] [loss (1)] [idx (NT)]

  float* esq = (float*)d_ws;                           // NK f32
  ushort* z2 = (ushort*)(esq + NK);                    // NT*512 bf16
  ushort* e2 = z2 + (size_t)NT * 512;                  // NK*512 bf16
  float* pdist = (float*)(e2 + (size_t)NK * 512);      // NT*NSP f32
  int* pidx = (int*)(pdist + (size_t)NT * NSP);        // NT*NSP i32
  float* lpart = (float*)(pidx + (size_t)NT * NSP);    // NT/4 f32

  vq_cvt<<<NT / 4, 256, 0, stream>>>(z, z2);
  vq_cvt<<<NK / 4, 256, 0, stream>>>(emb, e2);
  vq_esq<<<NK / 4, 256, 0, stream>>>(emb, esq);
  vq_mfma<<<4096, 512, 0, stream>>>(z2, e2, esq, pdist, pidx);
  vq_gather<<<NT / 4, 256, 0, stream>>>(z, emb, pdist, pidx, out, lpart);
  vq_finalize<<<1, 256, 0, stream>>>(lpart, out);
}